// Round 2
// baseline (444.849 us; speedup 1.0000x reference)
//
#include <hip/hip_runtime.h>

#define SEQ 512
#define NB  512
#define NT  96

typedef float f2 __attribute__((ext_vector_type(2)));

__device__ __forceinline__ f2 fma2(float ex, float ey, float c, f2 a) {
    f2 e; e.x = ex; e.y = ey;
    f2 cc; cc.x = c; cc.y = c;
    return e * cc + a;   // v_pk_fma_f32
}

// One block = 2 batches packed as float2. Thread j (0..95) owns tag-column j
// for both batches. Forward recursion in shifted-exp domain with lag-2 shift
// (d = lv[0] from step i-2) so only ONE barrier per step is needed.
__launch_bounds__(96)
__global__ void crf_fwd2(const float* __restrict__ logits,
                         const int*   __restrict__ tags,
                         const int*   __restrict__ mask,
                         const float* __restrict__ trans,
                         const float* __restrict__ startt,
                         const float* __restrict__ endt,
                         float* __restrict__ out)
{
    const int bb = blockIdx.x;
    const int b0 = 2 * bb, b1 = 2 * bb + 1;
    const int j = threadIdx.x;              // 0..95
    const float* emA = logits + (size_t)b0 * SEQ * NT;
    const float* emB = logits + (size_t)b1 * SEQ * NT;

    __shared__ __align__(16) f2 e_buf[2][NT];
    __shared__ f2  d_buf[2];
    __shared__ f2  red[NT];
    __shared__ float num_red[NT];
    __shared__ int tg_s[2][SEQ];
    __shared__ int2 mk2[SEQ];

    for (int i = j; i < SEQ; i += NT) {
        tg_s[0][i] = tags[(size_t)b0 * SEQ + i];
        tg_s[1][i] = tags[(size_t)b1 * SEQ + i];
        mk2[i] = make_int2(mask[(size_t)b0 * SEQ + i], mask[(size_t)b1 * SEQ + i]);
    }

    // expT column j in registers
    float col[NT];
#pragma unroll
    for (int k = 0; k < NT; ++k) col[k] = __expf(trans[k * NT + j]);

    // init: alpha0 = start + em[0]
    f2 lv; lv.x = startt[j] + emA[j]; lv.y = startt[j] + emB[j];
    f2 C;  C.x = 0.f; C.y = 0.f;
    if (j == 0) { d_buf[0] = lv; d_buf[1] = lv; }

    // register-rotated emission prefetch, depth 3
    f2 emq1, emq2, emq3;
    emq1.x = emA[1 * NT + j]; emq1.y = emB[1 * NT + j];
    emq2.x = emA[2 * NT + j]; emq2.y = emB[2 * NT + j];
    emq3.x = emA[3 * NT + j]; emq3.y = emB[3 * NT + j];
    __syncthreads();

    for (int i = 1; i < SEQ; ++i) {
        const int cur = i & 1;
        const f2 d = d_buf[cur];            // lag-2 shift (lv[0] from step i-2)
        f2 e; e.x = __expf(lv.x - d.x); e.y = __expf(lv.y - d.y);
        e_buf[cur][j] = e;

        // prefetch emission row for step i+3
        f2 emn; emn.x = 0.f; emn.y = 0.f;
        if (i + 3 < SEQ) { emn.x = emA[(i + 3) * NT + j]; emn.y = emB[(i + 3) * NT + j]; }
        const int mA = mk2[i].x, mB = mk2[i].y;
        __syncthreads();                    // the ONLY barrier per step

        const float4* e4 = (const float4*)&e_buf[cur][0];   // 2 packed e-pairs per read
        f2 a0, a1, a2, a3;
        a0.x=0.f;a0.y=0.f;a1.x=0.f;a1.y=0.f;a2.x=0.f;a2.y=0.f;a3.x=0.f;a3.y=0.f;
#pragma unroll
        for (int m = 0; m < NT / 2; m += 4) {
            const float4 w0 = e4[m + 0];
            const float4 w1 = e4[m + 1];
            const float4 w2 = e4[m + 2];
            const float4 w3 = e4[m + 3];
            a0 = fma2(w0.x, w0.y, col[2 * m + 0], a0);
            a0 = fma2(w0.z, w0.w, col[2 * m + 1], a0);
            a1 = fma2(w1.x, w1.y, col[2 * m + 2], a1);
            a1 = fma2(w1.z, w1.w, col[2 * m + 3], a1);
            a2 = fma2(w2.x, w2.y, col[2 * m + 4], a2);
            a2 = fma2(w2.z, w2.w, col[2 * m + 5], a2);
            a3 = fma2(w3.x, w3.y, col[2 * m + 6], a3);
            a3 = fma2(w3.z, w3.w, col[2 * m + 7], a3);
        }
        const f2 v = (a0 + a1) + (a2 + a3);

        f2 lvn; lvn.x = __logf(v.x) + emq1.x; lvn.y = __logf(v.y) + emq1.y;
        if (mA) { lv.x = lvn.x; C.x += d.x; }
        if (mB) { lv.y = lvn.y; C.y += d.y; }
        if (j == 0) d_buf[cur] = lv;        // shift for step i+2 (ordered by i+1's barrier)
        emq1 = emq2; emq2 = emq3; emq3 = emn;
    }

    // ---- denominator inputs ----
    red[j].x = lv.x + endt[j];
    red[j].y = lv.y + endt[j];

    // ---- numerator partials (strided over steps, both batches) ----
    float part = 0.f;
    for (int i = 1 + j; i < SEQ; i += NT) {
        if (mk2[i].x) {
            const int tp = tg_s[0][i - 1], tc = tg_s[0][i];
            part += trans[tp * NT + tc] + emA[i * NT + tc];
        }
        if (mk2[i].y) {
            const int tp = tg_s[1][i - 1], tc = tg_s[1][i];
            part += trans[tp * NT + tc] + emB[i * NT + tc];
        }
    }
    num_red[j] = part;
    __syncthreads();

    if (j == 0) {
        f2 m2 = red[0];
        for (int k = 1; k < NT; ++k) { m2.x = fmaxf(m2.x, red[k].x); m2.y = fmaxf(m2.y, red[k].y); }
        f2 s2; s2.x = 0.f; s2.y = 0.f;
        for (int k = 0; k < NT; ++k) { s2.x += __expf(red[k].x - m2.x); s2.y += __expf(red[k].y - m2.y); }
        const float denom = (C.x + m2.x + __logf(s2.x)) + (C.y + m2.y + __logf(s2.y));

        float num = startt[tg_s[0][0]] + emA[tg_s[0][0]]
                  + startt[tg_s[1][0]] + emB[tg_s[1][0]];
        for (int k = 0; k < NT; ++k) num += num_red[k];
        int cA = 0, cB = 0;
        for (int i = 0; i < SEQ; ++i) { cA += mk2[i].x; cB += mk2[i].y; }
        num += endt[tg_s[0][cA - 1]] + endt[tg_s[1][cB - 1]];

        atomicAdd(out, num - denom);
    }
}

extern "C" void kernel_launch(void* const* d_in, const int* in_sizes, int n_in,
                              void* d_out, int out_size, void* d_ws, size_t ws_size,
                              hipStream_t stream)
{
    const float* logits = (const float*)d_in[0];
    const int*   tags   = (const int*)  d_in[1];
    const int*   mask   = (const int*)  d_in[2];
    const float* trans  = (const float*)d_in[3];
    const float* startt = (const float*)d_in[4];
    const float* endt   = (const float*)d_in[5];
    float* out = (float*)d_out;

    hipMemsetAsync(out, 0, out_size * sizeof(float), stream);
    crf_fwd2<<<NB / 2, NT, 0, stream>>>(logits, tags, mask, trans,
                                        startt, endt, out);
}

// Round 3
// 297.223 us; speedup vs baseline: 1.4967x; 1.4967x over previous
//
#include <hip/hip_runtime.h>

#define SEQ 512
#define NB  512
#define NT  96
#define RR  4
#define TPB (NT * RR)   // 384 threads = 6 waves

// One block = one batch. Threads (r,j): r = k-slice row (0..3), j = tag column.
// Split-K forward recursion in shifted-exp domain (lag-2 uniform shift d):
//   row0: e[j] = exp(lv[j] - d)  -> e_buf
//   all:  part[j][r] = sum_{q<24} e[24r+q] * expT[24r+q][j]
//   row0: v[j] = sum_r part[j][r]; lv[j] = log(v)+em[i][j]; C += d
__launch_bounds__(TPB)
__global__ void crf_fwd_split(const float* __restrict__ logits,
                              const int*   __restrict__ tags,
                              const int*   __restrict__ mask,
                              const float* __restrict__ trans,
                              const float* __restrict__ startt,
                              const float* __restrict__ endt,
                              float* __restrict__ out)
{
    const int b = blockIdx.x;
    const int t = threadIdx.x;
    const int r = t / NT;
    const int j = t - r * NT;
    const float* em = logits + (size_t)b * SEQ * NT;

    __shared__ __align__(16) float e_buf[NT];
    __shared__ __align__(16) float part[NT][RR];
    __shared__ float d_buf[2];
    __shared__ float red[NT];
    __shared__ float num_red[TPB];
    __shared__ int tg_s[SEQ];
    __shared__ int mk_s[SEQ];

    for (int i = t; i < SEQ; i += TPB) {
        tg_s[i] = tags[(size_t)b * SEQ + i];
        mk_s[i] = mask[(size_t)b * SEQ + i];
    }

    // expT slice: col[q] = exp(T[24r+q][j])
    float col[24];
#pragma unroll
    for (int q = 0; q < 24; ++q)
        col[q] = __expf(trans[(24 * r + q) * NT + j]);

    float lv = 0.f, C = 0.f, d = 0.f;
    float emq1 = 0.f, emq2 = 0.f, emq3 = 0.f;
    if (r == 0) {
        lv = startt[j] + em[j];            // alpha0
        if (j == 0) { d_buf[0] = lv; d_buf[1] = lv; }
        emq1 = em[1 * NT + j];
        emq2 = em[2 * NT + j];
        emq3 = em[3 * NT + j];
    }
    __syncthreads();
    if (r == 0) d = d_buf[0];              // shift for step 1 (= lv0[0])

    for (int i = 1; i < SEQ; ++i) {
        if (r == 0) e_buf[j] = __expf(lv - d);
        __syncthreads();                    // B1: e ready

        // row0 prefetches emission row i+3 (overlaps FMA section)
        float emn = 0.f;
        if (r == 0 && i + 3 < SEQ) emn = em[(i + 3) * NT + j];

        const float4* e4 = (const float4*)e_buf + 6 * r;
        float a0 = 0.f, a1 = 0.f, a2 = 0.f, a3 = 0.f;
#pragma unroll
        for (int q = 0; q < 6; ++q) {
            const float4 ev = e4[q];        // broadcast reads, conflict-free
            a0 = fmaf(ev.x, col[4 * q + 0], a0);
            a1 = fmaf(ev.y, col[4 * q + 1], a1);
            a2 = fmaf(ev.z, col[4 * q + 2], a2);
            a3 = fmaf(ev.w, col[4 * q + 3], a3);
        }
        part[j][r] = (a0 + a1) + (a2 + a3);
        const int mk = mk_s[i];
        __syncthreads();                    // B2: partials ready

        if (r == 0) {
            const float dn = d_buf[(i + 1) & 1];     // shift for step i+1 (lag-2)
            const float4 p4 = *(const float4*)part[j];
            const float v = (p4.x + p4.y) + (p4.z + p4.w);
            const float lvn = __logf(v) + emq1;
            if (mk) { lv = lvn; C += d; }
            if (j == 0) d_buf[i & 1] = lv;           // publish lv_i[0]
            d = dn;
            emq1 = emq2; emq2 = emq3; emq3 = emn;
        }
    }

    // ---- denominator inputs ----
    if (r == 0) red[j] = lv + endt[j];

    // ---- numerator partials over all 384 threads ----
    float pn = 0.f;
    for (int i = 1 + t; i < SEQ; i += TPB) {
        if (mk_s[i]) {
            const int tp = tg_s[i - 1], tc = tg_s[i];
            pn += trans[tp * NT + tc] + em[i * NT + tc];
        }
    }
    num_red[t] = pn;
    __syncthreads();

    if (t == 0) {
        float m = red[0];
        for (int k = 1; k < NT; ++k) m = fmaxf(m, red[k]);
        float s = 0.f;
        for (int k = 0; k < NT; ++k) s += __expf(red[k] - m);
        const float denom = C + m + __logf(s);

        float num = startt[tg_s[0]] + em[tg_s[0]];
        for (int k = 0; k < TPB; ++k) num += num_red[k];
        int cnt = 0;
        for (int i = 0; i < SEQ; ++i) cnt += mk_s[i];
        num += endt[tg_s[cnt - 1]];

        atomicAdd(out, num - denom);
    }
}

extern "C" void kernel_launch(void* const* d_in, const int* in_sizes, int n_in,
                              void* d_out, int out_size, void* d_ws, size_t ws_size,
                              hipStream_t stream)
{
    const float* logits = (const float*)d_in[0];
    const int*   tags   = (const int*)  d_in[1];
    const int*   mask   = (const int*)  d_in[2];
    const float* trans  = (const float*)d_in[3];
    const float* startt = (const float*)d_in[4];
    const float* endt   = (const float*)d_in[5];
    float* out = (float*)d_out;

    hipMemsetAsync(out, 0, out_size * sizeof(float), stream);
    crf_fwd_split<<<NB, TPB, 0, stream>>>(logits, tags, mask, trans,
                                          startt, endt, out);
}